// Round 2
// baseline (380.495 us; speedup 1.0000x reference)
//
#include <hip/hip_runtime.h>
#include <hip/hip_bf16.h>
#include <stdint.h>

// B=4096, D_IN=1024, D_OUT=1024, P=16. All inputs f32, output f32.
// out[b,o] = sum_p m[b,p] * ( dot(x[b], W[p,o,:]) + c[p,o] )
// m[b,p]   = sig_p / (sum_q sig_q + 1e-6), sig_p = 1/(1+exp(score_p))
// score_p  = dot(x[b], Asum[p]) - bsum[p];  Asum[p,d]=sum_k A[p,k,d]; bsum[p]=sum_k b[p,k]
//
// f32 path for scores/m (precision-critical); bf16 MFMA for the 0.137 PFLOP
// mixture GEMM with per-p row-scaling fused into the accumulator merge.

typedef __attribute__((ext_vector_type(4))) float f32x4;
typedef __attribute__((ext_vector_type(8))) short bf16x8;

#define WBF_OFF   0u           // 16x1024x1024 bf16 = 32MB
#define XBF_OFF   33554432u    // 4096x1024 bf16 = 8MB
#define ASUM_OFF  41943040u    // 16x1024 f32 = 64KB
#define BSUM_OFF  42008576u    // 16 f32 (padded to 256B)
#define M_OFF     42008832u    // 4096x16 f32 = 256KB
#define PART_OFF  50331648u    // 2 x (4096x1024 f32) = 32MB split-p partials

__device__ __forceinline__ unsigned short f2bf(float f) {
  unsigned u = __builtin_bit_cast(unsigned, f);
  unsigned r = (u + 0x7fffu + ((u >> 16) & 1u)) >> 16;  // RNE
  return (unsigned short)r;
}

__device__ __forceinline__ void gload_lds16(const void* g, void* l) {
  __builtin_amdgcn_global_load_lds(
      (const __attribute__((address_space(1))) void*)g,
      (__attribute__((address_space(3))) void*)l, 16, 0, 0);
}

// ---- zero Asum + reduce bsum -------------------------------------------------
__global__ void prep_init(const float* __restrict__ b, float* __restrict__ Asum,
                          float* __restrict__ bsum) {
  const int p = blockIdx.x;   // 16
  const int t = threadIdx.x;  // 256
  float4* az = (float4*)(Asum + p * 1024);
  az[t] = make_float4(0.f, 0.f, 0.f, 0.f);
  const float* bp = b + (size_t)p * 1024;
  float s = 0.f;
  for (int i = t; i < 1024; i += 256) s += bp[i];
  __shared__ float red[256];
  red[t] = s;
  __syncthreads();
  for (int off = 128; off > 0; off >>= 1) {
    if (t < off) red[t] += red[t + off];
    __syncthreads();
  }
  if (t == 0) bsum[p] = red[0];
}

// ---- Asum[p,d] += partial over a k-chunk ------------------------------------
__global__ void asum_acc(const float* __restrict__ A, float* __restrict__ Asum) {
  const int p = blockIdx.x >> 4, kc = blockIdx.x & 15;  // 256 blocks
  const int t = threadIdx.x;                            // 256
  const float4* Ap = (const float4*)(A + (size_t)p * 1048576 + (size_t)kc * 65536);
  float sx = 0.f, sy = 0.f, sz = 0.f, sw = 0.f;
#pragma unroll 8
  for (int k = 0; k < 64; ++k) {
    float4 v = Ap[k * 256 + t];
    sx += v.x; sy += v.y; sz += v.z; sw += v.w;
  }
  float* dst = Asum + p * 1024 + t * 4;
  atomicAdd(dst + 0, sx); atomicAdd(dst + 1, sy);
  atomicAdd(dst + 2, sz); atomicAdd(dst + 3, sw);
}

// ---- f32 -> bf16 (vectorized, grid-stride) ----------------------------------
__global__ void convert_bf16(const float* __restrict__ src,
                             unsigned short* __restrict__ dst, int n4) {
  int i = blockIdx.x * blockDim.x + threadIdx.x;
  const int stride = gridDim.x * blockDim.x;
  for (; i < n4; i += stride) {
    float4 v = ((const float4*)src)[i];
    uint2 o;
    o.x = (unsigned)f2bf(v.x) | ((unsigned)f2bf(v.y) << 16);
    o.y = (unsigned)f2bf(v.z) | ((unsigned)f2bf(v.w) << 16);
    ((uint2*)dst)[i] = o;
  }
}

// ---- memberships m[b,p] in f32 (one wave per row b) --------------------------
__global__ void memberships(const float* __restrict__ x, const float* __restrict__ Asum,
                            const float* __restrict__ bsum, float* __restrict__ m) {
  const int wave = threadIdx.x >> 6, lane = threadIdx.x & 63;
  const int b = blockIdx.x * 4 + wave;  // 1024 blocks * 4 waves
  const float* xb = x + (size_t)b * 1024;
  float xr[16];
#pragma unroll
  for (int i = 0; i < 16; ++i) xr[i] = xb[i * 64 + lane];
  float myE = 0.f, sumE = 0.f;
#pragma unroll
  for (int p = 0; p < 16; ++p) {
    const float* ap = Asum + p * 1024;
    float s = 0.f;
#pragma unroll
    for (int i = 0; i < 16; ++i) s += xr[i] * ap[i * 64 + lane];
#pragma unroll
    for (int off = 32; off > 0; off >>= 1) s += __shfl_xor(s, off, 64);
    const float score = s - bsum[p];
    const float e = 1.f / (1.f + __expf(score));  // sigmoid(-score); saturates cleanly
    sumE += e;
    if ((lane & 15) == p) myE = e;
  }
  const float mv = myE / (sumE + 1e-6f);
  if (lane < 16) m[(size_t)b * 16 + lane] = mv;
}

// ---- main fused mixture GEMM -------------------------------------------------
// 128x128 tile, 4 waves (2x2), 16x16x32 bf16 MFMA, BK=32, double-buffered LDS
// staged via global_load_lds width=16. Per p: K=1024 into temp acc, then
// master += m[row,p]*(acc + c[p,col]).  SPLIT: 512 blocks, 8 experts each,
// write partials (c-term deferred to reduce).  !SPLIT: 256 blocks, all 16.
template <bool SPLIT>
__global__ __launch_bounds__(256, 2) void moe_gemm(
    const unsigned short* __restrict__ xbf,  // [4096][1024] bf16
    const unsigned short* __restrict__ wbf,  // [16][1024][1024] bf16
    const float* __restrict__ mptr,          // [4096][16]
    const float* __restrict__ c,             // [16][1024]
    float* __restrict__ dst)                 // out or partial base
{
  __shared__ __align__(16) unsigned char lds[2 * 16384];  // 2 x (A 8KB + B 8KB)
  __shared__ __align__(16) float m_lds[128 * 16];

  const int tid = threadIdx.x;
  const int bid = blockIdx.x;
  const int s = SPLIT ? (bid >> 8) : 0;
  const int tile = bid & 255;
  const int bt = tile >> 3, ot = tile & 7;
  const int brow = bt << 7, ocol = ot << 7;
  const int p0 = s * 8;          // 0 unless SPLIT && upper half
  const int PC = SPLIT ? 8 : 16;

  const int lane = tid & 63;
  const int wv = tid >> 6;
  const int wr = wv >> 1, wc = wv & 1;

  // stage m rows for this b-tile: 2048 contiguous floats
  {
    const float4* msrc = (const float4*)(mptr + (size_t)brow * 16);
    float4* mdst = (float4*)m_lds;
    mdst[tid] = msrc[tid];
    mdst[256 + tid] = msrc[256 + tid];
  }

  // stage one 128x32 A-tile + 128x32 B-tile (16KB) into buffer `buf`
  // local step u in [0, PC*32): p = p0 + (u>>5), k0 = (u&31)*32
  auto stage = [&](int buf, int u) {
    const int p = p0 + (u >> 5);
    const int k0 = (u & 31) << 5;
    const unsigned short* Ag = xbf + (size_t)brow * 1024 + k0;
    const unsigned short* Bg = wbf + (size_t)p * 1048576 + (size_t)ocol * 1024 + k0;
    unsigned char* base = lds + buf * 16384;
#pragma unroll
    for (int r = 0; r < 4; ++r) {
      const int e = ((r & 1) << 8) + tid;  // entry index within A or B half
      const int row = e >> 2, seg = e & 3;
      const unsigned short* g = (r < 2 ? Ag : Bg) + (size_t)row * 1024 + seg * 8;
      unsigned char* l = base + (r >= 2 ? 8192 : 0) +
                         ((((r & 1) << 8) + (tid & ~63)) << 4);  // wave-uniform dest
      gload_lds16(g, l);
    }
  };

  auto compute = [&](int buf, f32x4 (&acc)[4][4]) {
    const unsigned char* base = lds + buf * 16384;
    const unsigned char* Ab = base + ((wr * 64 + (lane & 15)) << 6) + ((lane >> 4) << 4);
    const unsigned char* Bb = base + 8192 + ((wc * 64 + (lane & 15)) << 6) + ((lane >> 4) << 4);
    bf16x8 a[4], b[4];
#pragma unroll
    for (int i = 0; i < 4; ++i) {
      a[i] = *(const bf16x8*)(Ab + i * 1024);  // +16 rows * 64B
      b[i] = *(const bf16x8*)(Bb + i * 1024);
    }
#pragma unroll
    for (int mi = 0; mi < 4; ++mi)
#pragma unroll
      for (int ni = 0; ni < 4; ++ni)
        acc[mi][ni] = __builtin_amdgcn_mfma_f32_16x16x32_bf16(a[mi], b[ni], acc[mi][ni], 0, 0, 0);
  };

  const f32x4 zv = {0.f, 0.f, 0.f, 0.f};
  f32x4 master[4][4];
#pragma unroll
  for (int mi = 0; mi < 4; ++mi)
#pragma unroll
    for (int ni = 0; ni < 4; ++ni) master[mi][ni] = zv;

  int cur = 0;
  stage(0, 0);

  for (int pi = 0; pi < PC; ++pi) {
    const int p = p0 + pi;
    f32x4 acc[4][4];
#pragma unroll
    for (int mi = 0; mi < 4; ++mi)
#pragma unroll
      for (int ni = 0; ni < 4; ++ni) acc[mi][ni] = zv;

#pragma unroll 2
    for (int ks = 0; ks < 32; ++ks) {
      const int u = pi * 32 + ks;
      __syncthreads();                       // staged buf[cur] ready; reads of buf[cur^1] done
      if (u + 1 < PC * 32) stage(cur ^ 1, u + 1);
      compute(cur, acc);
      cur ^= 1;
    }

    // merge: master += m[row,p] * (acc [+ c[p,col] if fused])
    float cvn[4] = {0.f, 0.f, 0.f, 0.f};
    if constexpr (!SPLIT) {
#pragma unroll
      for (int ni = 0; ni < 4; ++ni)
        cvn[ni] = c[(size_t)p * 1024 + ocol + wc * 64 + ni * 16 + (lane & 15)];
    }
#pragma unroll
    for (int mi = 0; mi < 4; ++mi)
#pragma unroll
      for (int j = 0; j < 4; ++j) {
        const int lrow = wr * 64 + mi * 16 + ((lane >> 4) << 2) + j;
        const float ms = m_lds[lrow * 16 + p];
#pragma unroll
        for (int ni = 0; ni < 4; ++ni) {
          if constexpr (SPLIT) master[mi][ni][j] += ms * acc[mi][ni][j];
          else                 master[mi][ni][j] += ms * (acc[mi][ni][j] + cvn[ni]);
        }
      }
  }

  float* ob = SPLIT ? (dst + (size_t)s * 4194304) : dst;
#pragma unroll
  for (int mi = 0; mi < 4; ++mi)
#pragma unroll
    for (int j = 0; j < 4; ++j) {
      const int grow = brow + wr * 64 + mi * 16 + ((lane >> 4) << 2) + j;
#pragma unroll
      for (int ni = 0; ni < 4; ++ni) {
        const int gcol = ocol + wc * 64 + ni * 16 + (lane & 15);
        ob[(size_t)grow * 1024 + gcol] = master[mi][ni][j];
      }
    }
}

// ---- split-p reduction + m@c term -------------------------------------------
__global__ void reduce_out(const float* __restrict__ part, const float* __restrict__ m,
                           const float* __restrict__ c, float* __restrict__ out) {
  const int b = blockIdx.x;   // 4096
  const int t = threadIdx.x;  // 256
  __shared__ float msh[16];
  if (t < 16) msh[t] = m[(size_t)b * 16 + t];
  __syncthreads();
  const int o = t * 4;
  const float* p0 = part + (size_t)b * 1024;
  const float* p1 = part + 4194304 + (size_t)b * 1024;
  float4 a = *(const float4*)(p0 + o);
  float4 bq = *(const float4*)(p1 + o);
  float rx = a.x + bq.x, ry = a.y + bq.y, rz = a.z + bq.z, rw = a.w + bq.w;
#pragma unroll
  for (int p = 0; p < 16; ++p) {
    const float mp = msh[p];
    float4 cv = *(const float4*)(c + (size_t)p * 1024 + o);
    rx += mp * cv.x; ry += mp * cv.y; rz += mp * cv.z; rw += mp * cv.w;
  }
  *(float4*)(out + (size_t)b * 1024 + o) = make_float4(rx, ry, rz, rw);
}

extern "C" void kernel_launch(void* const* d_in, const int* in_sizes, int n_in,
                              void* d_out, int out_size, void* d_ws, size_t ws_size,
                              hipStream_t stream) {
  const float* x = (const float*)d_in[0];
  const float* A = (const float*)d_in[1];
  const float* b = (const float*)d_in[2];
  const float* W = (const float*)d_in[3];
  const float* c = (const float*)d_in[4];
  float* out = (float*)d_out;
  char* ws = (char*)d_ws;

  unsigned short* wbf = (unsigned short*)(ws + WBF_OFF);
  unsigned short* xbf = (unsigned short*)(ws + XBF_OFF);
  float* Asum = (float*)(ws + ASUM_OFF);
  float* bsum = (float*)(ws + BSUM_OFF);
  float* mm = (float*)(ws + M_OFF);
  float* part = (float*)(ws + PART_OFF);

  prep_init<<<16, 256, 0, stream>>>(b, Asum, bsum);
  asum_acc<<<256, 256, 0, stream>>>(A, Asum);
  convert_bf16<<<4096, 256, 0, stream>>>(W, wbf, 16777216 / 4);
  convert_bf16<<<1024, 256, 0, stream>>>(x, xbf, 4194304 / 4);
  memberships<<<1024, 256, 0, stream>>>(x, Asum, bsum, mm);

  if (ws_size >= (size_t)PART_OFF + 2ull * 16777216ull) {
    // split-p x2: 512 blocks = 2 blocks/CU for latency hiding
    moe_gemm<true><<<512, 256, 0, stream>>>(xbf, wbf, mm, c, part);
    reduce_out<<<4096, 256, 0, stream>>>(part, mm, c, out);
  } else {
    moe_gemm<false><<<256, 256, 0, stream>>>(xbf, wbf, mm, c, out);
  }
}

// Round 8
// 377.916 us; speedup vs baseline: 1.0068x; 1.0068x over previous
//
#include <hip/hip_runtime.h>
#include <hip/hip_bf16.h>
#include <stdint.h>

// B=4096, D_IN=1024, D_OUT=1024, P=16. All inputs f32, output f32.
// out[b,o] = sum_p m[b,p] * ( dot(x[b], W[p,o,:]) + c[p,o] )
// m[b,p]   = sig_p / (sum_q sig_q + 1e-6), sig_p = 1/(1+exp(score_p))
// score_p  = dot(x[b], Asum[p]) - bsum[p];  Asum[p,d]=sum_k A[p,k,d]; bsum[p]=sum_k b[p,k]
//
// History: R2 PASS 380us (gemm 192, SPLIT=2, occ 21%). R3 (NS=4+swizzle) FAIL.
// R4 (NS=4, R2-exact decode) FAIL 90.25 => NS=4 regime itself broken (cause
// unresolved; suspect occupancy-dependent hazard). R7: gemm byte-identical to
// R2 (proven). Prep path reworked: no atomics (partial-sum + final), x-convert
// fused into memberships, prep_init absorbed. 7 launches -> 6.
// (R7 was an infra failure - this is the same kernel resubmitted.)

typedef __attribute__((ext_vector_type(4))) float f32x4;
typedef __attribute__((ext_vector_type(8))) short bf16x8;

#define WBF_OFF   0u           // 16x1024x1024 bf16 = 32MB
#define XBF_OFF   33554432u    // 4096x1024 bf16 = 8MB
#define ASUM_OFF  41943040u    // 16x1024 f32 = 64KB
#define BSUM_OFF  42008576u    // 16 f32 (padded)
#define M_OFF     42008832u    // 4096x16 f32 = 256KB (ends 42270976)
#define APART_OFF 44040192u    // 16kc x 16p x 1024 f32 = 1MB (ends 45088768)
#define PART_OFF  50331648u    // 2 x (4096x1024 f32) = 32MB split-p partials

__device__ __forceinline__ unsigned short f2bf(float f) {
  unsigned u = __builtin_bit_cast(unsigned, f);
  unsigned r = (u + 0x7fffu + ((u >> 16) & 1u)) >> 16;  // RNE
  return (unsigned short)r;
}

__device__ __forceinline__ void gload_lds16(const void* g, void* l) {
  __builtin_amdgcn_global_load_lds(
      (const __attribute__((address_space(1))) void*)g,
      (__attribute__((address_space(3))) void*)l, 16, 0, 0);
}

// ---- Asum stage 1: per-(p,kc) partial sums, no atomics, no init ------------
__global__ void asum_part(const float* __restrict__ A, float* __restrict__ apart) {
  const int p = blockIdx.x >> 4, kc = blockIdx.x & 15;  // 256 blocks
  const int t = threadIdx.x;                            // 256
  const float4* Ap = (const float4*)(A + (size_t)p * 1048576 + (size_t)kc * 65536);
  float sx = 0.f, sy = 0.f, sz = 0.f, sw = 0.f;
#pragma unroll 8
  for (int k = 0; k < 64; ++k) {
    float4 v = Ap[k * 256 + t];
    sx += v.x; sy += v.y; sz += v.z; sw += v.w;
  }
  ((float4*)apart)[((size_t)kc * 16 + p) * 256 + t] = make_float4(sx, sy, sz, sw);
}

// ---- Asum stage 2: sum 16 partials -> Asum[p]; also bsum[p] ----------------
__global__ void asum_final(const float* __restrict__ apart, const float* __restrict__ b,
                           float* __restrict__ Asum, float* __restrict__ bsum) {
  const int p = blockIdx.x;   // 16
  const int t = threadIdx.x;  // 256
  float4 acc = make_float4(0.f, 0.f, 0.f, 0.f);
#pragma unroll
  for (int kc = 0; kc < 16; ++kc) {
    float4 v = ((const float4*)apart)[((size_t)kc * 16 + p) * 256 + t];
    acc.x += v.x; acc.y += v.y; acc.z += v.z; acc.w += v.w;
  }
  ((float4*)(Asum + p * 1024))[t] = acc;
  // bsum[p] = sum of b[p][:]
  float4 bv = ((const float4*)b)[(size_t)p * 256 + t];
  float s = bv.x + bv.y + bv.z + bv.w;
  __shared__ float red[256];
  red[t] = s;
  __syncthreads();
  for (int off = 128; off > 0; off >>= 1) {
    if (t < off) red[t] += red[t + off];
    __syncthreads();
  }
  if (t == 0) bsum[p] = red[0];
}

// ---- f32 -> bf16 for W (vectorized, grid-stride) ---------------------------
__global__ void convert_bf16(const float* __restrict__ src,
                             unsigned short* __restrict__ dst, int n4) {
  int i = blockIdx.x * blockDim.x + threadIdx.x;
  const int stride = gridDim.x * blockDim.x;
  for (; i < n4; i += stride) {
    float4 v = ((const float4*)src)[i];
    uint2 o;
    o.x = (unsigned)f2bf(v.x) | ((unsigned)f2bf(v.y) << 16);
    o.y = (unsigned)f2bf(v.z) | ((unsigned)f2bf(v.w) << 16);
    ((uint2*)dst)[i] = o;
  }
}

// ---- memberships (f32) + x -> bf16 conversion, one wave per row ------------
__global__ void memberships_fused(const float* __restrict__ x, const float* __restrict__ Asum,
                                  const float* __restrict__ bsum, float* __restrict__ m,
                                  unsigned short* __restrict__ xbf) {
  const int wave = threadIdx.x >> 6, lane = threadIdx.x & 63;
  const int b = blockIdx.x * 4 + wave;  // 1024 blocks * 4 waves
  const float4* xrow4 = (const float4*)(x + (size_t)b * 1024);
  float4 xv[4];
#pragma unroll
  for (int i = 0; i < 4; ++i) xv[i] = xrow4[i * 64 + lane];
  // write bf16 copy of this row (coalesced ushort4 = 8B/lane)
  ushort4* xbo = (ushort4*)(xbf + (size_t)b * 1024);
#pragma unroll
  for (int i = 0; i < 4; ++i) {
    ushort4 h;
    h.x = f2bf(xv[i].x); h.y = f2bf(xv[i].y);
    h.z = f2bf(xv[i].z); h.w = f2bf(xv[i].w);
    xbo[i * 64 + lane] = h;
  }
  float myE = 0.f, sumE = 0.f;
#pragma unroll
  for (int p = 0; p < 16; ++p) {
    const float4* ap4 = (const float4*)(Asum + p * 1024);
    float s = 0.f;
#pragma unroll
    for (int i = 0; i < 4; ++i) {
      float4 av = ap4[i * 64 + lane];
      s += xv[i].x * av.x + xv[i].y * av.y + xv[i].z * av.z + xv[i].w * av.w;
    }
#pragma unroll
    for (int off = 32; off > 0; off >>= 1) s += __shfl_xor(s, off, 64);
    const float score = s - bsum[p];
    const float e = 1.f / (1.f + __expf(score));  // sigmoid(-score)
    sumE += e;
    if ((lane & 15) == p) myE = e;
  }
  const float mv = myE / (sumE + 1e-6f);
  if (lane < 16) m[(size_t)b * 16 + lane] = mv;
}

// ---- main fused mixture GEMM (BYTE-IDENTICAL to R2's proven version) -------
// 128x128 tile, 4 waves (2x2), 16x16x32 bf16 MFMA, BK=32, double-buffered LDS
// staged via global_load_lds width=16. Per p: K=1024 into temp acc, then
// master += m[row,p]*(acc + c[p,col]).  SPLIT: 512 blocks, 8 experts each,
// write partials (c-term deferred to reduce).  !SPLIT: 256 blocks, all 16.
template <bool SPLIT>
__global__ __launch_bounds__(256, 2) void moe_gemm(
    const unsigned short* __restrict__ xbf,  // [4096][1024] bf16
    const unsigned short* __restrict__ wbf,  // [16][1024][1024] bf16
    const float* __restrict__ mptr,          // [4096][16]
    const float* __restrict__ c,             // [16][1024]
    float* __restrict__ dst)                 // out or partial base
{
  __shared__ __align__(16) unsigned char lds[2 * 16384];  // 2 x (A 8KB + B 8KB)
  __shared__ __align__(16) float m_lds[128 * 16];

  const int tid = threadIdx.x;
  const int bid = blockIdx.x;
  const int s = SPLIT ? (bid >> 8) : 0;
  const int tile = bid & 255;
  const int bt = tile >> 3, ot = tile & 7;
  const int brow = bt << 7, ocol = ot << 7;
  const int p0 = s * 8;          // 0 unless SPLIT && upper half
  const int PC = SPLIT ? 8 : 16;

  const int lane = tid & 63;
  const int wv = tid >> 6;
  const int wr = wv >> 1, wc = wv & 1;

  // stage m rows for this b-tile: 2048 contiguous floats
  {
    const float4* msrc = (const float4*)(mptr + (size_t)brow * 16);
    float4* mdst = (float4*)m_lds;
    mdst[tid] = msrc[tid];
    mdst[256 + tid] = msrc[256 + tid];
  }

  // stage one 128x32 A-tile + 128x32 B-tile (16KB) into buffer `buf`
  // local step u in [0, PC*32): p = p0 + (u>>5), k0 = (u&31)*32
  auto stage = [&](int buf, int u) {
    const int p = p0 + (u >> 5);
    const int k0 = (u & 31) << 5;
    const unsigned short* Ag = xbf + (size_t)brow * 1024 + k0;
    const unsigned short* Bg = wbf + (size_t)p * 1048576 + (size_t)ocol * 1024 + k0;
    unsigned char* base = lds + buf * 16384;
#pragma unroll
    for (int r = 0; r < 4; ++r) {
      const int e = ((r & 1) << 8) + tid;  // entry index within A or B half
      const int row = e >> 2, seg = e & 3;
      const unsigned short* g = (r < 2 ? Ag : Bg) + (size_t)row * 1024 + seg * 8;
      unsigned char* l = base + (r >= 2 ? 8192 : 0) +
                         ((((r & 1) << 8) + (tid & ~63)) << 4);  // wave-uniform dest
      gload_lds16(g, l);
    }
  };

  auto compute = [&](int buf, f32x4 (&acc)[4][4]) {
    const unsigned char* base = lds + buf * 16384;
    const unsigned char* Ab = base + ((wr * 64 + (lane & 15)) << 6) + ((lane >> 4) << 4);
    const unsigned char* Bb = base + 8192 + ((wc * 64 + (lane & 15)) << 6) + ((lane >> 4) << 4);
    bf16x8 a[4], b[4];
#pragma unroll
    for (int i = 0; i < 4; ++i) {
      a[i] = *(const bf16x8*)(Ab + i * 1024);  // +16 rows * 64B
      b[i] = *(const bf16x8*)(Bb + i * 1024);
    }
#pragma unroll
    for (int mi = 0; mi < 4; ++mi)
#pragma unroll
      for (int ni = 0; ni < 4; ++ni)
        acc[mi][ni] = __builtin_amdgcn_mfma_f32_16x16x32_bf16(a[mi], b[ni], acc[mi][ni], 0, 0, 0);
  };

  const f32x4 zv = {0.f, 0.f, 0.f, 0.f};
  f32x4 master[4][4];
#pragma unroll
  for (int mi = 0; mi < 4; ++mi)
#pragma unroll
    for (int ni = 0; ni < 4; ++ni) master[mi][ni] = zv;

  int cur = 0;
  stage(0, 0);

  for (int pi = 0; pi < PC; ++pi) {
    const int p = p0 + pi;
    f32x4 acc[4][4];
#pragma unroll
    for (int mi = 0; mi < 4; ++mi)
#pragma unroll
      for (int ni = 0; ni < 4; ++ni) acc[mi][ni] = zv;

#pragma unroll 2
    for (int ks = 0; ks < 32; ++ks) {
      const int u = pi * 32 + ks;
      __syncthreads();                       // staged buf[cur] ready; reads of buf[cur^1] done
      if (u + 1 < PC * 32) stage(cur ^ 1, u + 1);
      compute(cur, acc);
      cur ^= 1;
    }

    // merge: master += m[row,p] * (acc [+ c[p,col] if fused])
    float cvn[4] = {0.f, 0.f, 0.f, 0.f};
    if constexpr (!SPLIT) {
#pragma unroll
      for (int ni = 0; ni < 4; ++ni)
        cvn[ni] = c[(size_t)p * 1024 + ocol + wc * 64 + ni * 16 + (lane & 15)];
    }
#pragma unroll
    for (int mi = 0; mi < 4; ++mi)
#pragma unroll
      for (int j = 0; j < 4; ++j) {
        const int lrow = wr * 64 + mi * 16 + ((lane >> 4) << 2) + j;
        const float ms = m_lds[lrow * 16 + p];
#pragma unroll
        for (int ni = 0; ni < 4; ++ni) {
          if constexpr (SPLIT) master[mi][ni][j] += ms * acc[mi][ni][j];
          else                 master[mi][ni][j] += ms * (acc[mi][ni][j] + cvn[ni]);
        }
      }
  }

  float* ob = SPLIT ? (dst + (size_t)s * 4194304) : dst;
#pragma unroll
  for (int mi = 0; mi < 4; ++mi)
#pragma unroll
    for (int j = 0; j < 4; ++j) {
      const int grow = brow + wr * 64 + mi * 16 + ((lane >> 4) << 2) + j;
#pragma unroll
      for (int ni = 0; ni < 4; ++ni) {
        const int gcol = ocol + wc * 64 + ni * 16 + (lane & 15);
        ob[(size_t)grow * 1024 + gcol] = master[mi][ni][j];
      }
    }
}

// ---- split-p reduction + m@c term (R2-identical, 2 slabs) -------------------
__global__ void reduce_out(const float* __restrict__ part, const float* __restrict__ m,
                           const float* __restrict__ c, float* __restrict__ out) {
  const int b = blockIdx.x;   // 4096
  const int t = threadIdx.x;  // 256
  __shared__ float msh[16];
  if (t < 16) msh[t] = m[(size_t)b * 16 + t];
  __syncthreads();
  const int o = t * 4;
  const float* p0 = part + (size_t)b * 1024;
  const float* p1 = part + 4194304 + (size_t)b * 1024;
  float4 a = *(const float4*)(p0 + o);
  float4 bq = *(const float4*)(p1 + o);
  float rx = a.x + bq.x, ry = a.y + bq.y, rz = a.z + bq.z, rw = a.w + bq.w;
#pragma unroll
  for (int p = 0; p < 16; ++p) {
    const float mp = msh[p];
    float4 cv = *(const float4*)(c + (size_t)p * 1024 + o);
    rx += mp * cv.x; ry += mp * cv.y; rz += mp * cv.z; rw += mp * cv.w;
  }
  *(float4*)(out + (size_t)b * 1024 + o) = make_float4(rx, ry, rz, rw);
}

extern "C" void kernel_launch(void* const* d_in, const int* in_sizes, int n_in,
                              void* d_out, int out_size, void* d_ws, size_t ws_size,
                              hipStream_t stream) {
  const float* x = (const float*)d_in[0];
  const float* A = (const float*)d_in[1];
  const float* b = (const float*)d_in[2];
  const float* W = (const float*)d_in[3];
  const float* c = (const float*)d_in[4];
  float* out = (float*)d_out;
  char* ws = (char*)d_ws;

  unsigned short* wbf = (unsigned short*)(ws + WBF_OFF);
  unsigned short* xbf = (unsigned short*)(ws + XBF_OFF);
  float* Asum = (float*)(ws + ASUM_OFF);
  float* bsum = (float*)(ws + BSUM_OFF);
  float* mm = (float*)(ws + M_OFF);
  float* apart = (float*)(ws + APART_OFF);
  float* part = (float*)(ws + PART_OFF);

  asum_part<<<256, 256, 0, stream>>>(A, apart);
  asum_final<<<16, 256, 0, stream>>>(apart, b, Asum, bsum);
  convert_bf16<<<4096, 256, 0, stream>>>(W, wbf, 16777216 / 4);
  memberships_fused<<<1024, 256, 0, stream>>>(x, Asum, bsum, mm, xbf);

  if (ws_size >= (size_t)PART_OFF + 2ull * 16777216ull) {
    // split-p x2: 512 blocks = 2 blocks/CU (proven R2 config)
    moe_gemm<true><<<512, 256, 0, stream>>>(xbf, wbf, mm, c, part);
    reduce_out<<<4096, 256, 0, stream>>>(part, mm, c, out);
  } else {
    moe_gemm<false><<<256, 256, 0, stream>>>(xbf, wbf, mm, c, out);
  }
}

// Round 9
// 368.399 us; speedup vs baseline: 1.0328x; 1.0258x over previous
//
#include <hip/hip_runtime.h>
#include <hip/hip_bf16.h>
#include <stdint.h>

// B=4096, D_IN=1024, D_OUT=1024, P=16. All inputs f32, output f32.
// out[b,o] = sum_p m[b,p] * ( dot(x[b], W[p,o,:]) + c[p,o] )
// m[b,p]   = sig_p / (sum_q sig_q + 1e-6), sig_p = 1/(1+exp(score_p))
// score_p  = dot(x[b], Asum[p]) - bsum[p]
//
// History: R2/R8 PASS 380/378us (gemm 192us, 2 blocks/CU, grid-limited).
// R3/R4 (split-p x4 variants) FAIL - cause unresolved; suspects were
// launch_bounds(256,4), p-partition arith, or occupancy hazard.
// R9: occupancy probe with minimal delta = split-K x2 on top of the PROVEN
// split-p x2: grid 1024 (2kh x 2s x 256 tiles), p-partition identical to R8,
// launch_bounds stays (256,2), m_lds kept, stage/compute byte-identical.
// Only deltas: u->(p,k0) map gains kh*512 base, slab = kh*2+s (4 slabs).
// Fallback: ws too small -> R8-exact NSLAB=2 path (WRITE_SIZE distinguishes).

typedef __attribute__((ext_vector_type(4))) float f32x4;
typedef __attribute__((ext_vector_type(8))) short bf16x8;

#define WBF_OFF   0u           // 16x1024x1024 bf16 = 32MB
#define XBF_OFF   33554432u    // 4096x1024 bf16 = 8MB
#define ASUM_OFF  41943040u    // 16x1024 f32 = 64KB
#define BSUM_OFF  42008576u    // 16 f32 (padded)
#define M_OFF     42008832u    // 4096x16 f32 = 256KB (ends 42270976)
#define APART_OFF 44040192u    // 16kc x 16p x 1024 f32 = 1MB (ends 45088768)
#define PART_OFF  50331648u    // up to 4 x (4096x1024 f32) = 64MB partials

__device__ __forceinline__ unsigned short f2bf(float f) {
  unsigned u = __builtin_bit_cast(unsigned, f);
  unsigned r = (u + 0x7fffu + ((u >> 16) & 1u)) >> 16;  // RNE
  return (unsigned short)r;
}

__device__ __forceinline__ void gload_lds16(const void* g, void* l) {
  __builtin_amdgcn_global_load_lds(
      (const __attribute__((address_space(1))) void*)g,
      (__attribute__((address_space(3))) void*)l, 16, 0, 0);
}

// ---- Asum stage 1: per-(p,kc) partial sums, no atomics, no init ------------
__global__ void asum_part(const float* __restrict__ A, float* __restrict__ apart) {
  const int p = blockIdx.x >> 4, kc = blockIdx.x & 15;  // 256 blocks
  const int t = threadIdx.x;                            // 256
  const float4* Ap = (const float4*)(A + (size_t)p * 1048576 + (size_t)kc * 65536);
  float sx = 0.f, sy = 0.f, sz = 0.f, sw = 0.f;
#pragma unroll 8
  for (int k = 0; k < 64; ++k) {
    float4 v = Ap[k * 256 + t];
    sx += v.x; sy += v.y; sz += v.z; sw += v.w;
  }
  ((float4*)apart)[((size_t)kc * 16 + p) * 256 + t] = make_float4(sx, sy, sz, sw);
}

// ---- Asum stage 2: sum 16 partials -> Asum[p]; also bsum[p] ----------------
__global__ void asum_final(const float* __restrict__ apart, const float* __restrict__ b,
                           float* __restrict__ Asum, float* __restrict__ bsum) {
  const int p = blockIdx.x;   // 16
  const int t = threadIdx.x;  // 256
  float4 acc = make_float4(0.f, 0.f, 0.f, 0.f);
#pragma unroll
  for (int kc = 0; kc < 16; ++kc) {
    float4 v = ((const float4*)apart)[((size_t)kc * 16 + p) * 256 + t];
    acc.x += v.x; acc.y += v.y; acc.z += v.z; acc.w += v.w;
  }
  ((float4*)(Asum + p * 1024))[t] = acc;
  float4 bv = ((const float4*)b)[(size_t)p * 256 + t];
  float s = bv.x + bv.y + bv.z + bv.w;
  __shared__ float red[256];
  red[t] = s;
  __syncthreads();
  for (int off = 128; off > 0; off >>= 1) {
    if (t < off) red[t] += red[t + off];
    __syncthreads();
  }
  if (t == 0) bsum[p] = red[0];
}

// ---- f32 -> bf16 for W (vectorized, grid-stride) ---------------------------
__global__ void convert_bf16(const float* __restrict__ src,
                             unsigned short* __restrict__ dst, int n4) {
  int i = blockIdx.x * blockDim.x + threadIdx.x;
  const int stride = gridDim.x * blockDim.x;
  for (; i < n4; i += stride) {
    float4 v = ((const float4*)src)[i];
    uint2 o;
    o.x = (unsigned)f2bf(v.x) | ((unsigned)f2bf(v.y) << 16);
    o.y = (unsigned)f2bf(v.z) | ((unsigned)f2bf(v.w) << 16);
    ((uint2*)dst)[i] = o;
  }
}

// ---- memberships (f32) + x -> bf16 conversion, one wave per row ------------
__global__ void memberships_fused(const float* __restrict__ x, const float* __restrict__ Asum,
                                  const float* __restrict__ bsum, float* __restrict__ m,
                                  unsigned short* __restrict__ xbf) {
  const int wave = threadIdx.x >> 6, lane = threadIdx.x & 63;
  const int b = blockIdx.x * 4 + wave;  // 1024 blocks * 4 waves
  const float4* xrow4 = (const float4*)(x + (size_t)b * 1024);
  float4 xv[4];
#pragma unroll
  for (int i = 0; i < 4; ++i) xv[i] = xrow4[i * 64 + lane];
  ushort4* xbo = (ushort4*)(xbf + (size_t)b * 1024);
#pragma unroll
  for (int i = 0; i < 4; ++i) {
    ushort4 h;
    h.x = f2bf(xv[i].x); h.y = f2bf(xv[i].y);
    h.z = f2bf(xv[i].z); h.w = f2bf(xv[i].w);
    xbo[i * 64 + lane] = h;
  }
  float myE = 0.f, sumE = 0.f;
#pragma unroll
  for (int p = 0; p < 16; ++p) {
    const float4* ap4 = (const float4*)(Asum + p * 1024);
    float s = 0.f;
#pragma unroll
    for (int i = 0; i < 4; ++i) {
      float4 av = ap4[i * 64 + lane];
      s += xv[i].x * av.x + xv[i].y * av.y + xv[i].z * av.z + xv[i].w * av.w;
    }
#pragma unroll
    for (int off = 32; off > 0; off >>= 1) s += __shfl_xor(s, off, 64);
    const float score = s - bsum[p];
    const float e = 1.f / (1.f + __expf(score));  // sigmoid(-score)
    sumE += e;
    if ((lane & 15) == p) myE = e;
  }
  const float mv = myE / (sumE + 1e-6f);
  if (lane < 16) m[(size_t)b * 16 + lane] = mv;
}

// ---- main fused mixture GEMM -------------------------------------------------
// 128x128 tile, 4 waves (2x2), 16x16x32 bf16 MFMA, BK=32, double-buffered LDS
// staged via global_load_lds width=16. Per expert p: accumulate its K-range
// into acc, then master += m[row,p]*acc (+c if NSLAB==1).
// NSLAB=4: split-p x2 AND split-K x2. bid = kh*512 + sg*256 + tile.
//   per block: PC=8 experts (p0=sg*8, SAME partition as proven NSLAB=2),
//   K-range [kh*512, kh*512+512), 16 ksteps/expert. slab = kh*2+sg.
// NSLAB=2: R8-exact proven path (sg=bid>>8, full K, slab=sg).
// NSLAB=1: monolithic, c fused.
template <int NSLAB>
__global__ __launch_bounds__(256, 2) void moe_gemm(
    const unsigned short* __restrict__ xbf,  // [4096][1024] bf16
    const unsigned short* __restrict__ wbf,  // [16][1024][1024] bf16
    const float* __restrict__ mptr,          // [4096][16]
    const float* __restrict__ c,             // [16][1024]
    float* __restrict__ dst)                 // out or partial base
{
  __shared__ __align__(16) unsigned char lds[2 * 16384];  // 2 x (A 8KB + B 8KB)
  __shared__ __align__(16) float m_lds[128 * 16];

  const int tid = threadIdx.x;
  const int bid = blockIdx.x;
  const int tile = bid & 255;
  const int bt = tile >> 3, ot = tile & 7;   // proven decode
  const int brow = bt << 7, ocol = ot << 7;

  const int sg = (NSLAB == 4) ? ((bid >> 8) & 1) : (NSLAB == 2 ? (bid >> 8) : 0);
  const int kh = (NSLAB == 4) ? (bid >> 9) : 0;
  const int PC = (NSLAB >= 2) ? 8 : 16;          // experts per block
  const int p0 = sg * 8;
  const int KSTEPS = (NSLAB == 4) ? 16 : 32;     // 32B k-chunks per expert
  const int kbase = kh * 512;                    // k-range start (elements)
  const int TOT = PC * KSTEPS;                   // total staged chunks

  const int lane = tid & 63;
  const int wv = tid >> 6;
  const int wr = wv >> 1, wc = wv & 1;

  // stage m rows for this b-tile: 2048 contiguous floats
  {
    const float4* msrc = (const float4*)(mptr + (size_t)brow * 16);
    float4* mdst = (float4*)m_lds;
    mdst[tid] = msrc[tid];
    mdst[256 + tid] = msrc[256 + tid];
  }

  // stage one 128x32 A-tile + 128x32 B-tile (16KB) into buffer `buf`
  auto stage = [&](int buf, int u) {
    const int p = p0 + (u / KSTEPS);             // KSTEPS is pow2 constexpr
    const int k0 = kbase + (u % KSTEPS) * 32;
    const unsigned short* Ag = xbf + (size_t)brow * 1024 + k0;
    const unsigned short* Bg = wbf + (size_t)p * 1048576 + (size_t)ocol * 1024 + k0;
    unsigned char* base = lds + buf * 16384;
#pragma unroll
    for (int r = 0; r < 4; ++r) {
      const int e = ((r & 1) << 8) + tid;  // entry index within A or B half
      const int row = e >> 2, seg = e & 3;
      const unsigned short* g = (r < 2 ? Ag : Bg) + (size_t)row * 1024 + seg * 8;
      unsigned char* l = base + (r >= 2 ? 8192 : 0) +
                         ((((r & 1) << 8) + (tid & ~63)) << 4);  // wave-uniform dest
      gload_lds16(g, l);
    }
  };

  auto compute = [&](int buf, f32x4 (&acc)[4][4]) {
    const unsigned char* base = lds + buf * 16384;
    const unsigned char* Ab = base + ((wr * 64 + (lane & 15)) << 6) + ((lane >> 4) << 4);
    const unsigned char* Bb = base + 8192 + ((wc * 64 + (lane & 15)) << 6) + ((lane >> 4) << 4);
    bf16x8 a[4], b[4];
#pragma unroll
    for (int i = 0; i < 4; ++i) {
      a[i] = *(const bf16x8*)(Ab + i * 1024);  // +16 rows * 64B
      b[i] = *(const bf16x8*)(Bb + i * 1024);
    }
#pragma unroll
    for (int mi = 0; mi < 4; ++mi)
#pragma unroll
      for (int ni = 0; ni < 4; ++ni)
        acc[mi][ni] = __builtin_amdgcn_mfma_f32_16x16x32_bf16(a[mi], b[ni], acc[mi][ni], 0, 0, 0);
  };

  const f32x4 zv = {0.f, 0.f, 0.f, 0.f};
  f32x4 master[4][4];
#pragma unroll
  for (int mi = 0; mi < 4; ++mi)
#pragma unroll
    for (int ni = 0; ni < 4; ++ni) master[mi][ni] = zv;

  int cur = 0;
  stage(0, 0);

  for (int pi = 0; pi < PC; ++pi) {
    const int p = p0 + pi;
    f32x4 acc[4][4];
#pragma unroll
    for (int mi = 0; mi < 4; ++mi)
#pragma unroll
      for (int ni = 0; ni < 4; ++ni) acc[mi][ni] = zv;

#pragma unroll 2
    for (int ks = 0; ks < KSTEPS; ++ks) {
      const int u = pi * KSTEPS + ks;
      __syncthreads();                       // staged buf[cur] ready; reads of buf[cur^1] done
      if (u + 1 < TOT) stage(cur ^ 1, u + 1);
      compute(cur, acc);
      cur ^= 1;
    }

    // merge: master += m[row,p] * (acc [+ c[p,col] if NSLAB==1])
    float cvn[4] = {0.f, 0.f, 0.f, 0.f};
    if constexpr (NSLAB == 1) {
#pragma unroll
      for (int ni = 0; ni < 4; ++ni)
        cvn[ni] = c[(size_t)p * 1024 + ocol + wc * 64 + ni * 16 + (lane & 15)];
    }
#pragma unroll
    for (int mi = 0; mi < 4; ++mi)
#pragma unroll
      for (int j = 0; j < 4; ++j) {
        const int lrow = wr * 64 + mi * 16 + ((lane >> 4) << 2) + j;
        const float ms = m_lds[lrow * 16 + p];
#pragma unroll
        for (int ni = 0; ni < 4; ++ni) {
          if constexpr (NSLAB == 1) master[mi][ni][j] += ms * (acc[mi][ni][j] + cvn[ni]);
          else                      master[mi][ni][j] += ms * acc[mi][ni][j];
        }
      }
  }

  const int slab = (NSLAB == 4) ? (kh * 2 + sg) : sg;  // 0 for NSLAB==1
  float* ob = dst + (size_t)slab * 4194304;
#pragma unroll
  for (int mi = 0; mi < 4; ++mi)
#pragma unroll
    for (int j = 0; j < 4; ++j) {
      const int grow = brow + wr * 64 + mi * 16 + ((lane >> 4) << 2) + j;
#pragma unroll
      for (int ni = 0; ni < 4; ++ni) {
        const int gcol = ocol + wc * 64 + ni * 16 + (lane & 15);
        ob[(size_t)grow * 1024 + gcol] = master[mi][ni][j];
      }
    }
}

// ---- partial reduction + m@c term -------------------------------------------
template <int NSLAB>
__global__ void reduce_out(const float* __restrict__ part, const float* __restrict__ m,
                           const float* __restrict__ c, float* __restrict__ out) {
  const int b = blockIdx.x;   // 4096
  const int t = threadIdx.x;  // 256
  __shared__ float msh[16];
  if (t < 16) msh[t] = m[(size_t)b * 16 + t];
  __syncthreads();
  const int o = t * 4;
  float rx = 0.f, ry = 0.f, rz = 0.f, rw = 0.f;
#pragma unroll
  for (int s = 0; s < NSLAB; ++s) {
    float4 a = *(const float4*)(part + (size_t)s * 4194304 + (size_t)b * 1024 + o);
    rx += a.x; ry += a.y; rz += a.z; rw += a.w;
  }
#pragma unroll
  for (int p = 0; p < 16; ++p) {
    const float mp = msh[p];
    float4 cv = *(const float4*)(c + (size_t)p * 1024 + o);
    rx += mp * cv.x; ry += mp * cv.y; rz += mp * cv.z; rw += mp * cv.w;
  }
  *(float4*)(out + (size_t)b * 1024 + o) = make_float4(rx, ry, rz, rw);
}

extern "C" void kernel_launch(void* const* d_in, const int* in_sizes, int n_in,
                              void* d_out, int out_size, void* d_ws, size_t ws_size,
                              hipStream_t stream) {
  const float* x = (const float*)d_in[0];
  const float* A = (const float*)d_in[1];
  const float* b = (const float*)d_in[2];
  const float* W = (const float*)d_in[3];
  const float* c = (const float*)d_in[4];
  float* out = (float*)d_out;
  char* ws = (char*)d_ws;

  unsigned short* wbf = (unsigned short*)(ws + WBF_OFF);
  unsigned short* xbf = (unsigned short*)(ws + XBF_OFF);
  float* Asum = (float*)(ws + ASUM_OFF);
  float* bsum = (float*)(ws + BSUM_OFF);
  float* mm = (float*)(ws + M_OFF);
  float* apart = (float*)(ws + APART_OFF);
  float* part = (float*)(ws + PART_OFF);

  asum_part<<<256, 256, 0, stream>>>(A, apart);
  asum_final<<<16, 256, 0, stream>>>(apart, b, Asum, bsum);
  convert_bf16<<<4096, 256, 0, stream>>>(W, wbf, 16777216 / 4);
  memberships_fused<<<1024, 256, 0, stream>>>(x, Asum, bsum, mm, xbf);

  const size_t need4 = (size_t)PART_OFF + 4ull * 16777216ull;
  const size_t need2 = (size_t)PART_OFF + 2ull * 16777216ull;
  if (ws_size >= need4) {
    // split-p x2 + split-K x2: 1024 blocks = 4 blocks/CU
    moe_gemm<4><<<1024, 256, 0, stream>>>(xbf, wbf, mm, c, part);
    reduce_out<4><<<4096, 256, 0, stream>>>(part, mm, c, out);
  } else if (ws_size >= need2) {
    // proven R2/R8 config
    moe_gemm<2><<<512, 256, 0, stream>>>(xbf, wbf, mm, c, part);
    reduce_out<2><<<4096, 256, 0, stream>>>(part, mm, c, out);
  } else {
    moe_gemm<1><<<256, 256, 0, stream>>>(xbf, wbf, mm, c, out);
  }
}